// Round 3
// baseline (269.609 us; speedup 1.0000x reference)
//
#include <hip/hip_runtime.h>
#include <math.h>

// FastLearnableEMA: y[b,t,c] = cumsum_t(x * w) / max(a^t, 1e-8)
//   a = clamp(sigmoid(logit_alpha), 1e-4, 1-1e-4)      [C]
//   w[t] = a^t * (t==0 ? 1 : (1-a))
// B=32, T=2048, C=512, fp32. Memory-bound (268 MB min HBM traffic).
//
// v4: same two stream-ordered float4 kernels as v3 (1 KB per wave-load;
// scalar-dword v1/v2 plateaued at ~2.8 TB/s), but partials live in a
// static __device__ array instead of d_ws: the harness re-poisons d_ws
// with a 512 MiB fill (~80 us, 84% of HBM peak) INSIDE the timed loop,
// which swallowed v3's entire gain. Static device globals are not
// poisoned and cost nothing per iteration.
//   K1: part[b,tb,c] = sum over 32-step t-block of x*w   (4 MB static)
//   K2: exclusive prefix over earlier t-blocks (L2-resident partials),
//       re-read x (LLC-resident after K1), emit y.
// No __syncthreads, no phase lockstep; stream order is the global barrier.

#define B_    32
#define T_    2048
#define C_    512
#define STEPS 32              // t-steps per partial block
#define NTB   (T_ / STEPS)    // 64 t-blocks
#define C4    (C_ / 4)        // 128 float4 columns
#define ROWS  (B_ * NTB)      // 2048 (b,tb) rows
#define BLK   512
#define RPB   (BLK / C4)      // 4 rows per block
#define GRID  (ROWS / RPB)    // 512 blocks -> 2 blocks/CU, 16 waves/CU

// 4 MB static scratch. K1 fully rewrites it before K2 reads it every
// invocation, so there is no cross-iteration stale-data dependence.
__device__ float g_part[ROWS * C_];

// lanes 0..63 of a wave cover consecutive c4 -> 1 KB contiguous per wave-load.

__global__ __launch_bounds__(BLK, 4)
void ema_partial_kernel(const float* __restrict__ x,
                        const float* __restrict__ logit_alpha) {
    const int tid = threadIdx.x;
    const int c4  = tid & (C4 - 1);
    const int row = blockIdx.x * RPB + (tid >> 7);   // (b,tb) row
    const int b   = row >> 6;                        // NTB == 64
    const int tb  = row & (NTB - 1);
    const int c   = c4 << 2;
    const int t0  = tb * STEPS;

    const float4 lav = *(const float4*)(logit_alpha + c);
    const float la4[4] = {lav.x, lav.y, lav.z, lav.w};

    float a[4], oma[4], ap[4], s[4];
    #pragma unroll
    for (int j = 0; j < 4; ++j) {
        float av = 1.0f / (1.0f + expf(-la4[j]));
        av = fminf(fmaxf(av, 1e-4f), 1.0f - 1e-4f);
        a[j]   = av;
        oma[j] = 1.0f - av;
        ap[j]  = exp2f((float)t0 * log2f(av));  // a^t0 (0 on underflow — those
        s[j]   = 0.0f;                          // weights are <1e-38 anyway)
    }

    const float* __restrict__ xp = x + ((size_t)b * T_ + t0) * C_ + c;
    #pragma unroll 8
    for (int i = 0; i < STEPS; ++i) {
        const float4 v = *(const float4*)(xp + (size_t)i * C_);
        const float xv[4] = {v.x, v.y, v.z, v.w};
        #pragma unroll
        for (int j = 0; j < 4; ++j) {
            const float w = (t0 + i == 0) ? 1.0f : ap[j] * oma[j];
            s[j] = fmaf(xv[j], w, s[j]);
            ap[j] *= a[j];
        }
    }
    *(float4*)(g_part + (size_t)row * C_ + c) = make_float4(s[0], s[1], s[2], s[3]);
}

__global__ __launch_bounds__(BLK, 4)
void ema_emit_kernel(const float* __restrict__ x,
                     const float* __restrict__ logit_alpha,
                     float* __restrict__ y) {
    const int tid = threadIdx.x;
    const int c4  = tid & (C4 - 1);
    const int row = blockIdx.x * RPB + (tid >> 7);
    const int b   = row >> 6;
    const int tb  = row & (NTB - 1);
    const int c   = c4 << 2;
    const int t0  = tb * STEPS;

    // ---- exclusive prefix over earlier t-blocks (independent float4 loads
    // from the 4 MB L2-resident partial array; wave-uniform trip count)
    float S[4] = {0.0f, 0.0f, 0.0f, 0.0f};
    {
        const float* __restrict__ pp = g_part + (size_t)(b * NTB) * C_ + c;
        for (int tbp = 0; tbp < tb; ++tbp) {
            const float4 v = *(const float4*)(pp + (size_t)tbp * C_);
            S[0] += v.x; S[1] += v.y; S[2] += v.z; S[3] += v.w;
        }
    }

    const float4 lav = *(const float4*)(logit_alpha + c);
    const float la4[4] = {lav.x, lav.y, lav.z, lav.w};

    float a[4], oma[4], ap[4], inva[4], invap[4];
    #pragma unroll
    for (int j = 0; j < 4; ++j) {
        float av = 1.0f / (1.0f + expf(-la4[j]));
        av = fminf(fmaxf(av, 1e-4f), 1.0f - 1e-4f);
        a[j]    = av;
        oma[j]  = 1.0f - av;
        inva[j] = 1.0f / av;
        const float l2a = log2f(av);
        ap[j]    = exp2f((float)t0 * l2a);
        invap[j] = exp2f(-(float)t0 * l2a);  // a^-t0; overflow->inf is clamped
    }                                        // to 1e8 below (matches EPS clamp)

    const float* __restrict__ xp = x + ((size_t)b * T_ + t0) * C_ + c;
    float* __restrict__ yp       = y + ((size_t)b * T_ + t0) * C_ + c;

    #pragma unroll 8
    for (int i = 0; i < STEPS; ++i) {
        const float4 v = *(const float4*)(xp + (size_t)i * C_);
        const float xv[4] = {v.x, v.y, v.z, v.w};
        float out[4];
        #pragma unroll
        for (int j = 0; j < 4; ++j) {
            const float w = (t0 + i == 0) ? 1.0f : ap[j] * oma[j];
            S[j] = fmaf(xv[j], w, S[j]);
            out[j] = S[j] * fminf(invap[j], 1e8f);
            ap[j]    *= a[j];
            invap[j] *= inva[j];
        }
        *(float4*)(yp + (size_t)i * C_) = make_float4(out[0], out[1], out[2], out[3]);
    }
}

extern "C" void kernel_launch(void* const* d_in, const int* in_sizes, int n_in,
                              void* d_out, int out_size, void* d_ws, size_t ws_size,
                              hipStream_t stream) {
    const float* x  = (const float*)d_in[0];   // [32, 2048, 512] fp32
    const float* la = (const float*)d_in[1];   // [512] fp32
    float* y = (float*)d_out;                  // [32, 2048, 512] fp32

    hipLaunchKernelGGL(ema_partial_kernel, dim3(GRID), dim3(BLK), 0, stream,
                       x, la);
    hipLaunchKernelGGL(ema_emit_kernel, dim3(GRID), dim3(BLK), 0, stream,
                       x, la, y);
}

// Round 4
// 257.532 us; speedup vs baseline: 1.0469x; 1.0469x over previous
//
#include <hip/hip_runtime.h>
#include <math.h>

// FastLearnableEMA: y[b,t,c] = cumsum_t(x * w) / max(a^t, 1e-8)
//   a = clamp(sigmoid(logit_alpha), 1e-4, 1-1e-4)      [C]
//   w[t] = a^t * (t==0 ? 1 : (1-a))
// B=32, T=2048, C=512, fp32. Memory-bound (268 MB min HBM traffic).
//
// v5: sequential-sweep access. v1/v2/v4 all plateaued at ~2.8 TB/s
// regardless of segment size (256B vs 1KB per wave-load) — the common
// factor was the stride-2KB column-walk (threads walking t), i.e. ~2k
// concurrent strided streams thrashing DRAM pages. The harness's own
// 512MiB fill and d2d float4 copy (sequential sweeps) hit 6.6/6.3 TB/s.
// So: every global access is now a contiguous block-level sweep, and the
// serial-in-t compute is decoupled from the access pattern via LDS.
//   K1: block owns contiguous 256KB slab (b, 128t, full C); reads it
//       front-to-back (8KB per step); mod-4 t-interleave per thread
//       (sums are order-independent); LDS-reduce -> part[b,slab,c] (1MB).
//   K2: same slab; prefix from L2-resident partials; 4 tiles of 32t:
//       stage 64KB seq -> serial cumsum in LDS (thread=channel,
//       conflict-free, in-place) -> store 64KB seq. 64KB LDS =
//       2 blocks/CU so stage and compute overlap across blocks.
// Fixed harness overhead (unconditional 512MiB d_ws poison fills ~80us
// + misc ~157us total) is outside kernel control.

#define B_    32
#define T_    2048
#define C_    512
#define SLAB  128             // t-steps per block
#define NS    (T_ / SLAB)     // 16 slabs per b
#define ROWS  (B_ * NS)       // 512 = grid for both kernels
#define BLK   512
#define TT    32              // t-rows per K2 LDS tile (64 KB)
#define NTILE (SLAB / TT)     // 4

// 1 MB static scratch (d_ws is re-poisoned inside the timed loop; static
// globals are not). K1 fully rewrites it before K2 reads it each launch.
__device__ float g_part[ROWS * C_];

__global__ __launch_bounds__(BLK, 4)
void ema_partial_kernel(const float* __restrict__ x,
                        const float* __restrict__ logit_alpha) {
    __shared__ float red[4][C_];          // 8 KB
    const int tid = threadIdx.x;
    const int c4  = tid & 127;            // float4 column
    const int tg  = tid >> 7;             // t mod 4 phase, 0..3
    const int row = blockIdx.x;           // (b, slab)
    const int b   = row >> 4;
    const int ts  = row & (NS - 1);
    const int t0  = ts * SLAB;
    const int c   = c4 << 2;

    const float4 lav = *(const float4*)(logit_alpha + c);
    const float la4[4] = {lav.x, lav.y, lav.z, lav.w};

    float a[4], oma[4], ap[4], r4[4], s[4];
    #pragma unroll
    for (int j = 0; j < 4; ++j) {
        float av = 1.0f / (1.0f + expf(-la4[j]));
        av = fminf(fmaxf(av, 1e-4f), 1.0f - 1e-4f);
        a[j]   = av;
        oma[j] = 1.0f - av;
        ap[j]  = exp2f((float)(t0 + tg) * log2f(av));  // a^(t0+tg); 0 on
        const float aa = av * av;                      // underflow is fine
        r4[j]  = aa * aa;                              // a^4 step ratio
        s[j]   = 0.0f;
    }

    // Block reads its 256KB slab front-to-back: step k touches one
    // contiguous 8KB line (4 t-rows x 2KB), threads (tg,c4) cover it.
    const float* __restrict__ xp = x + ((size_t)b * T_ + t0 + tg) * C_ + c;
    #pragma unroll 8
    for (int k = 0; k < SLAB / 4; ++k) {
        const float4 v = *(const float4*)(xp + (size_t)(k * 4) * C_);
        const float xv[4] = {v.x, v.y, v.z, v.w};
        const bool isz = (t0 + tg == 0) && (k == 0);   // t == 0
        #pragma unroll
        for (int j = 0; j < 4; ++j) {
            const float w = isz ? 1.0f : ap[j] * oma[j];
            s[j] = fmaf(xv[j], w, s[j]);
            ap[j] *= r4[j];
        }
    }

    // reduce the 4 mod-phases per channel, write slab chunk-sum
    *(float4*)(&red[tg][c]) = make_float4(s[0], s[1], s[2], s[3]);
    __syncthreads();
    if (tid < 128) {
        const float4 v0 = *(const float4*)(&red[0][tid << 2]);
        const float4 v1 = *(const float4*)(&red[1][tid << 2]);
        const float4 v2 = *(const float4*)(&red[2][tid << 2]);
        const float4 v3 = *(const float4*)(&red[3][tid << 2]);
        *(float4*)(g_part + (size_t)row * C_ + (tid << 2)) =
            make_float4(v0.x + v1.x + v2.x + v3.x,
                        v0.y + v1.y + v2.y + v3.y,
                        v0.z + v1.z + v2.z + v3.z,
                        v0.w + v1.w + v2.w + v3.w);
    }
}

__global__ __launch_bounds__(BLK, 4)
void ema_emit_kernel(const float* __restrict__ x,
                     const float* __restrict__ logit_alpha,
                     float* __restrict__ y) {
    __shared__ float xt[TT * C_];         // 64 KB -> 2 blocks/CU
    const int tid = threadIdx.x;          // == channel c
    const int row = blockIdx.x;
    const int b   = row >> 4;
    const int ts  = row & (NS - 1);
    const int t0  = ts * SLAB;

    // per-channel alpha state (scalar; thread = channel)
    const float z = logit_alpha[tid];
    float a = 1.0f / (1.0f + expf(-z));
    a = fminf(fmaxf(a, 1e-4f), 1.0f - 1e-4f);
    const float oma  = 1.0f - a;
    const float inva = 1.0f / a;
    const float l2a  = log2f(a);
    float ap    = exp2f((float)t0 * l2a);   // a^t0
    float invap = exp2f(-(float)t0 * l2a);  // a^-t0; overflow->inf clamped
                                            // to 1e8 below (matches EPS)
    // exclusive prefix over earlier slabs (L2-resident, coalesced dwords)
    float S = 0.0f;
    for (int p = 0; p < ts; ++p)
        S += g_part[(size_t)(b * NS + p) * C_ + tid];

    const float* __restrict__ xp = x + ((size_t)b * T_ + t0) * C_;
    float* __restrict__ yp       = y + ((size_t)b * T_ + t0) * C_;

    for (int tile = 0; tile < NTILE; ++tile) {
        // ---- stage 64KB sequentially: 512 threads x 8 float4
        const float* __restrict__ src = xp + (size_t)tile * TT * C_;
        #pragma unroll
        for (int k = 0; k < 8; ++k) {
            const int idx = k * BLK + tid;             // float4 index
            *(float4*)(&xt[idx << 2]) = *(const float4*)(src + ((size_t)idx << 2));
        }
        __syncthreads();

        // ---- serial per-channel cumsum in LDS (in-place y overwrite)
        float* col = xt + tid;                         // conflict-free column
        const bool zrow = (t0 == 0) && (tile == 0);
        #pragma unroll 8
        for (int i = 0; i < TT; ++i) {
            const float xv = col[(size_t)i * C_];
            const float w  = (zrow && i == 0) ? 1.0f : ap * oma;
            S = fmaf(xv, w, S);
            col[(size_t)i * C_] = S * fminf(invap, 1e8f);
            ap    *= a;
            invap *= inva;
        }
        __syncthreads();

        // ---- store 64KB sequentially
        float* __restrict__ dst = yp + (size_t)tile * TT * C_;
        #pragma unroll
        for (int k = 0; k < 8; ++k) {
            const int idx = k * BLK + tid;
            *(float4*)(dst + ((size_t)idx << 2)) = *(const float4*)(&xt[idx << 2]);
        }
        __syncthreads();   // xt reuse next tile
    }
}

extern "C" void kernel_launch(void* const* d_in, const int* in_sizes, int n_in,
                              void* d_out, int out_size, void* d_ws, size_t ws_size,
                              hipStream_t stream) {
    const float* x  = (const float*)d_in[0];   // [32, 2048, 512] fp32
    const float* la = (const float*)d_in[1];   // [512] fp32
    float* y = (float*)d_out;                  // [32, 2048, 512] fp32

    hipLaunchKernelGGL(ema_partial_kernel, dim3(ROWS), dim3(BLK), 0, stream,
                       x, la);
    hipLaunchKernelGGL(ema_emit_kernel, dim3(ROWS), dim3(BLK), 0, stream,
                       x, la, y);
}